// Round 10
// baseline (262.544 us; speedup 1.0000x reference)
//
#include <hip/hip_runtime.h>
#include <hip/hip_bf16.h>
#include <stdint.h>

#define T_SEQ   2048
#define NHEAD   16
#define NPAD1   3712   // 3072 (q) + 512 (latent) + 64 (k_pe) + 64 pad -> 29*128

typedef short bf16x8  __attribute__((ext_vector_type(8)));
typedef float f32x4   __attribute__((ext_vector_type(4)));
typedef float f32x16  __attribute__((ext_vector_type(16)));

__device__ __forceinline__ unsigned short f2bf(float f) {
  union { float f; uint32_t u; } v; v.f = f;
  uint32_t u = v.u;
  uint32_t r = u + 0x7FFF + ((u >> 16) & 1);   // RNE
  return (unsigned short)(r >> 16);
}

__device__ __forceinline__ void async16(const void* g, void* l) {
  __builtin_amdgcn_global_load_lds(
      (const __attribute__((address_space(1))) void*)g,
      (__attribute__((address_space(3))) void*)l, 16, 0, 0);
}

// ---------------- fused prep: convert hs + 4 weight transposes + pad + rope table --
__device__ __forceinline__ void tr32(const float* __restrict__ in,
    unsigned short* __restrict__ out, int R, int C, int bx, int by,
    float (*tile)[33], int tid) {
  int r0 = bx * 32, c0 = by * 32;
  int tx = tid & 31, ty = tid >> 5;
  for (int i = 0; i < 4; i++)
    tile[ty + i * 8][tx] = in[(size_t)(r0 + ty + i * 8) * C + c0 + tx];
  __syncthreads();
  for (int i = 0; i < 4; i++) {
    int c = ty + i * 8;
    out[(size_t)(c0 + c) * R + r0 + tx] = f2bf(tile[tx][c]);
  }
}

__global__ __launch_bounds__(256) void prep_kernel(
    const float* __restrict__ hs, const float* __restrict__ w_q,
    const float* __restrict__ w_kv_a, const float* __restrict__ w_kv_b,
    const float* __restrict__ w_o, const int* __restrict__ positions,
    unsigned short* __restrict__ hs_bf, unsigned short* __restrict__ wcat_t,
    unsigned short* __restrict__ wkvb_t, unsigned short* __restrict__ wo_t,
    float* __restrict__ rope_tab) {             // T x 64 f32, interleaved (c,s)
  __shared__ float tile[32][33];
  int bid = blockIdx.x, tid = threadIdx.x;
  if (bid < 4096) {                              // convert hs -> bf16
    int i = (bid * 256 + tid) * 4;
    float4 v = *(const float4*)(hs + i);
    ushort4 o; o.x = f2bf(v.x); o.y = f2bf(v.y); o.z = f2bf(v.z); o.w = f2bf(v.w);
    *(ushort4*)(hs_bf + i) = o;
  } else if (bid < 4096 + 6144) {                // w_q^T (2048x3072)
    int l = bid - 4096;
    tr32(w_q, wcat_t, 2048, 3072, l & 63, l >> 6, tile, tid);
  } else if (bid < 4096 + 6144 + 1152) {         // w_kv_a^T (2048x576)
    int l = bid - (4096 + 6144);
    tr32(w_kv_a, wcat_t + (size_t)3072 * 2048, 2048, 576, l & 63, l >> 6, tile, tid);
  } else if (bid < 4096 + 6144 + 1152 + 2048) {  // w_kv_b^T (512x4096)
    int l = bid - (4096 + 6144 + 1152);
    tr32(w_kv_b, wkvb_t, 512, 4096, l & 15, l >> 4, tile, tid);
  } else if (bid < 4096 + 6144 + 1152 + 2048 + 4096) {  // w_o^T (2048x2048)
    int l = bid - (4096 + 6144 + 1152 + 2048);
    tr32(w_o, wo_t, 2048, 2048, l & 63, l >> 6, tile, tid);
  } else if (bid < 17600) {                      // zero pad rows 3648..3711 of wcat_t
    int l = bid - (4096 + 6144 + 1152 + 2048 + 4096);
    uint4 z = (uint4){0, 0, 0, 0};
    *(uint4*)(wcat_t + (size_t)3648 * 2048 + (size_t)(l * 256 + tid) * 8) = z;
  } else {                                       // rope cos/sin table (trig lives HERE,
    int l = bid - 17600;                         //  never in the GEMM epilogue)
    int t = l * 8 + (tid >> 5), p = tid & 31;
    float pos = (float)positions[t];
    float inv_freq = powf(10000.f, -(float)(2 * p) / 64.f);
    float c, s; sincosf(pos * inv_freq, &s, &c);
    rope_tab[(size_t)t * 64 + 2 * p]     = c;
    rope_tab[(size_t)t * 64 + 2 * p + 1] = s;
  }
}

// ---------------- GEMM: C(MxN) = A(MxK) bf16 @ B^T(NxK) bf16 ----------------
// TM x 128 tile, BK=64, 4 waves of (TM/2)x64. Double-buffered global_load_lds,
// single barrier per K-step (proven best: r9, 252.7us total). Chunk-XOR LDS
// swizzle both-sides. EPI: 0 = f32 C, 1 = bf16 C, 2 = fused q-epilogue.
// EPI==2 is CALL-FREE and TRIG-FREE (libm in epilogue spills acc: r4/r5).
template<int TM, int EPI>
__global__ __launch_bounds__(256) void gemm_bt_kernel(
    const unsigned short* __restrict__ A, const unsigned short* __restrict__ B,
    void* __restrict__ Cv, int M, int N, int K,
    unsigned short* __restrict__ q_full, const float* __restrict__ rope_tab) {
  constexpr int MT = TM / 32;                    // 16-row subtiles per wave
  __shared__ __align__(16) unsigned short Asm[2][TM * 64];
  __shared__ __align__(16) unsigned short Bsm[2][128 * 64];
  int tid = threadIdx.x, wid = tid >> 6, lane = tid & 63;
  int lrow = lane & 15, lquad = lane >> 4;
  int m0 = blockIdx.x * TM, n0 = blockIdx.y * 128;
  int wm = (wid & 1) * (TM / 2), wn = (wid >> 1) * 64;

  int row_s = tid >> 3;                          // 32 rows per 256-thread pass
  int cc_s = (tid & 7) ^ (row_s & 7);            // pre-swizzled source 16B chunk
  const unsigned short* Ag[MT];
  const unsigned short* Bg[4];
  #pragma unroll
  for (int p = 0; p < MT; p++) Ag[p] = A + (size_t)(m0 + row_s + p * 32) * K + cc_s * 8;
  #pragma unroll
  for (int p = 0; p < 4; p++)  Bg[p] = B + (size_t)(n0 + row_s + p * 32) * K + cc_s * 8;

  f32x4 acc[MT][4];
  #pragma unroll
  for (int i = 0; i < MT; i++)
    #pragma unroll
    for (int j = 0; j < 4; j++) acc[i][j] = (f32x4){0.f,0.f,0.f,0.f};

  #pragma unroll
  for (int p = 0; p < MT; p++) async16(Ag[p], &Asm[0][(tid + p * 256) * 8]);
  #pragma unroll
  for (int p = 0; p < 4; p++)  async16(Bg[p], &Bsm[0][(tid + p * 256) * 8]);

  int cur = 0;
  for (int k0 = 0; k0 < K; k0 += 64) {
    __syncthreads();                      // drains DMA for buf[cur]; prev readers done
    if (k0 + 64 < K) {
      int nxt = cur ^ 1, kk = k0 + 64;
      #pragma unroll
      for (int p = 0; p < MT; p++) async16(Ag[p] + kk, &Asm[nxt][(tid + p * 256) * 8]);
      #pragma unroll
      for (int p = 0; p < 4; p++)  async16(Bg[p] + kk, &Bsm[nxt][(tid + p * 256) * 8]);
    }
    const unsigned short* As = Asm[cur];
    const unsigned short* Bs = Bsm[cur];
    int xr = (lrow & 7);
    #pragma unroll
    for (int kk = 0; kk < 2; kk++) {             // two K=32 halves of the 64-step
      int cz = ((kk * 4 + lquad) ^ xr) * 8;      // swizzled chunk (shorts)
      bf16x8 af[MT], bfr[4];
      #pragma unroll
      for (int mt = 0; mt < MT; mt++)
        af[mt] = *(const bf16x8*)(As + (wm + mt * 16 + lrow) * 64 + cz);
      #pragma unroll
      for (int nt = 0; nt < 4; nt++)
        bfr[nt] = *(const bf16x8*)(Bs + (wn + nt * 16 + lrow) * 64 + cz);
      #pragma unroll
      for (int mt = 0; mt < MT; mt++)
        #pragma unroll
        for (int nt = 0; nt < 4; nt++)
          acc[mt][nt] = __builtin_amdgcn_mfma_f32_16x16x32_bf16(af[mt], bfr[nt], acc[mt][nt], 0, 0, 0);
    }
    cur ^= 1;
  }

  if constexpr (EPI == 2) {
    const float scaling = 0.07216878364870323f;  // 192^-0.5
    float* qlat = (float*)Cv;                    // T x 640 (latent 512 | k_pe 64 | pad 64)
    #pragma unroll
    for (int nt = 0; nt < 4; nt++) {
      int colb = n0 + wn + nt * 16;              // wave-uniform, 16-aligned
      if (colb >= 3072) {                        // latent / k_pe / pad -> f32 narrow
        int col = colb - 3072 + lrow;
        #pragma unroll
        for (int mt = 0; mt < MT; mt++) {
          int row = m0 + wm + mt * 16 + lquad * 4;
          #pragma unroll
          for (int r = 0; r < 4; r++)
            qlat[(size_t)(row + r) * 640 + col] = acc[mt][nt][r];
        }
      } else {
        int h = colb / 192;
        int hm = colb - h * 192;                 // uniform; frag never straddles 192 or 128
        unsigned short* qh = q_full + (size_t)h * T_SEQ * 192;
        if (hm < 128) {                          // q_nope: scale only
          #pragma unroll
          for (int mt = 0; mt < MT; mt++) {
            int row = m0 + wm + mt * 16 + lquad * 4;
            #pragma unroll
            for (int r = 0; r < 4; r++)
              qh[(size_t)(row + r) * 192 + hm + lrow] = f2bf(acc[mt][nt][r] * scaling);
          }
        } else {                                 // q_pe: rope via table (no trig here!)
          int p2 = (hm - 128 + lrow) & ~1;       // 2*p, shared by lane pair
          int odd = lrow & 1;
          #pragma unroll
          for (int mt = 0; mt < MT; mt++) {
            int row = m0 + wm + mt * 16 + lquad * 4;
            #pragma unroll
            for (int r = 0; r < 4; r++) {
              int rg = row + r;
              float c = rope_tab[(size_t)rg * 64 + p2];
              float s = rope_tab[(size_t)rg * 64 + p2 + 1];
              float own = acc[mt][nt][r];
              float oth = __shfl_xor(own, 1, 64);
              float o = odd ? (own * c + oth * s)           // o2 = x2*c + x1*s
                            : (own * c - oth * s);          // o1 = x1*c - x2*s
              qh[(size_t)rg * 192 + hm + lrow] = f2bf(o * scaling);
            }
          }
        }
      }
    }
  } else {
    #pragma unroll
    for (int mt = 0; mt < MT; mt++)
      #pragma unroll
      for (int nt = 0; nt < 4; nt++) {
        int row = m0 + wm + mt * 16 + lquad * 4;
        int col = n0 + wn + nt * 16 + lrow;
        #pragma unroll
        for (int r = 0; r < 4; r++) {
          if (EPI == 1)
            ((unsigned short*)Cv)[(size_t)(row + r) * N + col] = f2bf(acc[mt][nt][r]);
          else
            ((float*)Cv)[(size_t)(row + r) * N + col] = acc[mt][nt][r];
        }
      }
  }
}

// ---------------- postproc1: rmsnorm + k_pe rope (table) + kv_a pack ----------------
__global__ __launch_bounds__(256) void postproc1_kernel(
    const float* __restrict__ q_lat,      // T x 640 (latent 512 | k_pe 64 | pad)
    const float* __restrict__ ln_w,       // 512
    const float* __restrict__ rope_tab,   // T x 64 (c,s interleaved)
    unsigned short* __restrict__ kv_a,    // T x 512 bf16
    unsigned short* __restrict__ k_pe)    // T x 64 bf16 (roped)
{
  int t = blockIdx.x, tid = threadIdx.x;
  const float* row = q_lat + (size_t)t * 640;

  float v0 = row[tid], v1 = row[256 + tid];
  float ss = v0 * v0 + v1 * v1;
  for (int m = 1; m < 64; m <<= 1) ss += __shfl_xor(ss, m, 64);
  __shared__ float red[4];
  if ((tid & 63) == 0) red[tid >> 6] = ss;
  __shared__ float kro[64];
  if (tid < 32) {
    float c = rope_tab[(size_t)t * 64 + 2 * tid];
    float s = rope_tab[(size_t)t * 64 + 2 * tid + 1];
    float x1 = row[512 + 2 * tid], x2 = row[512 + 2 * tid + 1];
    kro[2 * tid]     = x1 * c - x2 * s;
    kro[2 * tid + 1] = x2 * c + x1 * s;
  }
  __syncthreads();
  float rstd = rsqrtf((red[0] + red[1] + red[2] + red[3]) * (1.f / 512.f) + 1e-6f);
  kv_a[(size_t)t * 512 + tid]       = f2bf(v0 * rstd * ln_w[tid]);
  kv_a[(size_t)t * 512 + 256 + tid] = f2bf(v1 * rstd * ln_w[256 + tid]);
  if (tid < 64) k_pe[(size_t)t * 64 + tid] = f2bf(kro[tid]);
}

// ---------------- kvpost: vtrans (v_t) only — kpack eliminated ----------------
__global__ __launch_bounds__(256) void kvpost_kernel(
    const unsigned short* __restrict__ kv_b,   // T x 4096 bf16
    unsigned short* __restrict__ v_t) {        // NH x 128 x T bf16
  __shared__ unsigned short tile[32][41];
  int l = blockIdx.x, tid = threadIdx.x;       // 4096 = 16h x 4d x 64t blocks
  int h = l >> 8, t0 = (l & 63) * 32, d0 = ((l >> 6) & 3) * 32;
  int tx = tid & 31, ty = tid >> 5;
  for (int i = 0; i < 4; i++)
    tile[ty + i * 8][tx] = kv_b[(size_t)(t0 + ty + i * 8) * 4096 + h * 256 + 128 + d0 + tx];
  __syncthreads();
  for (int i = 0; i < 4; i++)
    v_t[((size_t)h * 128 + d0 + ty + i * 8) * T_SEQ + t0 + tx] = tile[tx][ty + i * 8];
}

// ---------------- flash attention: BM=64, BN=64, 32x32x16 MFMA, SPLIT-K JOBS ------
// r9 profile: Occupancy 13% — the (qb, 31-qb) pairing balances totals but the
// short block finishes early, leaving 4 waves/CU (1/SIMD) for most of the run.
// Fix: 48 jobs/head. qb>=16 split into two K-range halves (8-16 iters each,
// partial f32 O/L written unnormalized — valid because softmax here has NO
// running max, so partials combine by pure addition); qb<16 stay whole and
// write attn_out directly. 768 jobs: 512 resident + 256 backfill.
#define PP 76
#define PSTRIDE 8256                             // 64*128 O + 64 lsum, f32
__global__ __launch_bounds__(256, 2) void flash_kernel(
    const unsigned short* __restrict__ q_full,  // NH x T x 192 (pre-scaled)
    const unsigned short* __restrict__ kv_b,    // T x 4096
    const unsigned short* __restrict__ k_pe,    // T x 64 (roped)
    const unsigned short* __restrict__ v_t,     // NH x 128 x T
    unsigned short* __restrict__ attn_out,      // T x 2048
    float* __restrict__ part)                   // 512 x PSTRIDE f32
{
  __shared__ __align__(16) unsigned short Ksm[2][1536 * 8];  // 49152 B
  __shared__ __align__(16) unsigned short Vsm[1024 * 8];     // 16384 B
  __shared__ __align__(16) unsigned short Psm[64 * PP];      //  9728 B
  __shared__ float Lred[2][64];
  int h = blockIdx.x;
  int j = blockIdx.y;                          // job id 0..47
  int qb, k0t, k1t, pidx;
  if (j < 32) {                                // split jobs (long tiles qb>=16)
    qb = 16 + (j >> 1);
    int mid = (qb + 1) >> 1;
    if (j & 1) { k0t = mid; k1t = qb + 1; } else { k0t = 0; k1t = mid; }
    pidx = (h * 16 + (qb - 16)) * 2 + (j & 1);
  } else {                                     // whole jobs (qb<16), longest first
    qb = 47 - j; k0t = 0; k1t = qb + 1; pidx = -1;
  }
  int tid = threadIdx.x, wid = tid >> 6, lane = tid & 63;
  int l31 = lane & 31, l5 = lane >> 5, x7 = l31 & 7;
  int rq = wid & 1, kq = wid >> 1;             // row-half / key-half (dh = kq for PV)

  const unsigned short* vh = v_t + (size_t)h * 128 * T_SEQ;

  // K staging: per-lane source ptr + per-64-row stride (kv_b vs k_pe class)
  const unsigned short* pK[6]; int sK[6];
  #pragma unroll
  for (int j2 = 0; j2 < 6; j2++) {
    int s = tid + j2 * 256, row = s / 24, cm = s - row * 24;
    int c = cm ^ (row & 7);                    // swizzled 16B chunk of logical row
    if (c < 16) { pK[j2] = kv_b + (size_t)row * 4096 + h * 256 + c * 8; sK[j2] = 64 * 4096; }
    else        { pK[j2] = k_pe + (size_t)row * 64 + (c - 16) * 8;      sK[j2] = 64 * 64; }
  }
  int gV[4];
  #pragma unroll
  for (int j2 = 0; j2 < 4; j2++) {
    int s = tid + j2 * 256, d = s >> 3;
    gV[j2] = d * T_SEQ + ((s & 7) ^ (d & 7)) * 8;
  }
  // K frag offsets: key = kq*32+l31, chunk c8 = kc*2+l5 (XOR-unswizzle)
  int kxo[12];
  #pragma unroll
  for (int kc = 0; kc < 12; kc++)
    kxo[kc] = (kq * 32 + l31) * 192 + ((kc * 2 + l5) ^ x7) * 8;
  // V frag bases: d = kq*64 + ntv*32 + l31
  int vxb[2];
  #pragma unroll
  for (int ntv = 0; ntv < 2; ntv++) vxb[ntv] = (kq * 64 + ntv * 32 + l31) * 64;

  bf16x8 qf[12];
  {
    const unsigned short* qrow =
        q_full + ((size_t)h * T_SEQ + qb * 64 + rq * 32 + l31) * 192 + l5 * 8;
    #pragma unroll
    for (int kc = 0; kc < 12; kc++) qf[kc] = *(const bf16x8*)(qrow + kc * 16);
  }
  f32x16 oacc[2];
  for (int i = 0; i < 2; i++) oacc[i] = (f32x16)(0.f);
  float lsum[16];
  #pragma unroll
  for (int r = 0; r < 16; r++) lsum[r] = 0.f;
  int rl[16];                                   // C/D reg -> local row (32x32 layout)
  #pragma unroll
  for (int r = 0; r < 16; r++) rl[r] = (r & 3) + 8 * (r >> 2) + 4 * l5;

  // prologue: stage K(k0t) into buf 0
  #pragma unroll
  for (int j2 = 0; j2 < 6; j2++)
    async16(pK[j2] + (size_t)k0t * sK[j2], &Ksm[0][(tid + j2 * 256) * 8]);

  int cur = 0;
  for (int kb = k0t; kb < k1t; kb++) {
    __syncthreads();                            // K[cur] ready; prev PV readers done
    {                                           // stage V(kb); drains at sync2
      const unsigned short* vb = vh + kb * 64;
      #pragma unroll
      for (int j2 = 0; j2 < 4; j2++) async16(vb + gV[j2], &Vsm[(tid + j2 * 256) * 8]);
    }
    const unsigned short* Ks = Ksm[cur];
    f32x16 sacc = (f32x16)(0.f);
    #pragma unroll
    for (int kc = 0; kc < 12; kc++) {
      bf16x8 kf = *(const bf16x8*)(Ks + kxo[kc]);
      sacc = __builtin_amdgcn_mfma_f32_32x32x16_bf16(qf[kc], kf, sacc, 0, 0, 0);
    }
    if (kb == qb) {                             // mask diagonal tile
      int col_g = kb * 64 + kq * 32 + l31;
      int row_b = qb * 64 + rq * 32;
      #pragma unroll
      for (int r = 0; r < 16; r++)
        if (col_g > row_b + rl[r]) sacc[r] = -1e30f;
    }
    #pragma unroll
    for (int r = 0; r < 16; r++) {
      float p = __expf(sacc[r]);
      sacc[r] = p;
      lsum[r] += p;
    }
    #pragma unroll
    for (int r = 0; r < 16; r++)                // P C-layout -> Psm
      Psm[(rq * 32 + rl[r]) * PP + kq * 32 + l31] = f2bf(sacc[r]);
    __syncthreads();                            // V ready, P visible, K[cur] reads done
    if (kb + 1 < k1t) {                         // stage K(kb+1); drains at next sync1
      #pragma unroll
      for (int j2 = 0; j2 < 6; j2++)
        async16(pK[j2] + (size_t)(kb + 1) * sK[j2], &Ksm[cur ^ 1][(tid + j2 * 256) * 8]);
    }
    #pragma unroll
    for (int kc = 0; kc < 4; kc++) {            // O += P V
      bf16x8 pf = *(const bf16x8*)(Psm + (rq * 32 + l31) * PP + kc * 16 + l5 * 8);
      #pragma unroll
      for (int ntv = 0; ntv < 2; ntv++) {
        bf16x8 vf = *(const bf16x8*)(Vsm + vxb[ntv] + ((kc * 2 + l5) ^ x7) * 8);
        oacc[ntv] = __builtin_amdgcn_mfma_f32_32x32x16_bf16(pf, vf, oacc[ntv], 0, 0, 0);
      }
    }
    cur ^= 1;
  }

  // denominator: reduce over 32 key-lanes, then combine key-halves via LDS
  #pragma unroll
  for (int r = 0; r < 16; r++) {
    float s = lsum[r];
    s += __shfl_xor(s, 1, 64);
    s += __shfl_xor(s, 2, 64);
    s += __shfl_xor(s, 4, 64);
    s += __shfl_xor(s, 8, 64);
    s += __shfl_xor(s, 16, 64);
    lsum[r] = s;
  }
  if (l31 == 0)
    #pragma unroll
    for (int r = 0; r < 16; r++) Lred[kq][rq * 32 + rl[r]] = lsum[r];
  __syncthreads();
  if (pidx < 0) {                               // whole job: normalize + write bf16
    #pragma unroll
    for (int r = 0; r < 16; r++) {
      int row_l = rq * 32 + rl[r];
      float inv = 1.f / (Lred[0][row_l] + Lred[1][row_l]);
      int row_g = qb * 64 + row_l;
      #pragma unroll
      for (int ntv = 0; ntv < 2; ntv++)
        attn_out[(size_t)row_g * 2048 + h * 128 + kq * 64 + ntv * 32 + l31] =
            f2bf(oacc[ntv][r] * inv);
    }
  } else {                                      // split job: unnormalized f32 partials
    float* pb = part + (size_t)pidx * PSTRIDE;
    #pragma unroll
    for (int r = 0; r < 16; r++) {
      int row_l = rq * 32 + rl[r];
      #pragma unroll
      for (int ntv = 0; ntv < 2; ntv++)
        pb[row_l * 128 + kq * 64 + ntv * 32 + l31] = oacc[ntv][r];
    }
    if (tid < 64) pb[8192 + tid] = Lred[0][tid] + Lred[1][tid];
  }
}

// ---------------- combine: sum split partials, normalize, write bf16 --------------
__global__ __launch_bounds__(256) void combine_kernel(
    const float* __restrict__ part, unsigned short* __restrict__ attn_out) {
  int bx = blockIdx.x;                         // 256 = 16h x 16 split q-tiles
  int h = bx >> 4, q16 = bx & 15, qb = 16 + q16;
  size_t b0 = (size_t)((h * 16 + q16) * 2) * PSTRIDE;
  size_t b1 = b0 + PSTRIDE;
  __shared__ float Ls[64];
  int tid = threadIdx.x;
  if (tid < 64) Ls[tid] = part[b0 + 8192 + tid] + part[b1 + 8192 + tid];
  __syncthreads();
  for (int i = tid; i < 2048; i += 256) {      // 2048 float4 spans 64x128
    float4 a = *(const float4*)(part + b0 + (size_t)i * 4);
    float4 c = *(const float4*)(part + b1 + (size_t)i * 4);
    int row = i >> 5;
    float inv = 1.f / Ls[row];
    ushort4 o;
    o.x = f2bf((a.x + c.x) * inv); o.y = f2bf((a.y + c.y) * inv);
    o.z = f2bf((a.z + c.z) * inv); o.w = f2bf((a.w + c.w) * inv);
    *(ushort4*)(attn_out + (size_t)(qb * 64 + row) * 2048 + h * 128 + (i & 31) * 4) = o;
  }
}

// ---------------- launch ----------------
extern "C" void kernel_launch(void* const* d_in, const int* in_sizes, int n_in,
                              void* d_out, int out_size, void* d_ws, size_t ws_size,
                              hipStream_t stream) {
  const int*   positions = (const int*)d_in[0];
  const float* hs     = (const float*)d_in[1];
  const float* w_q    = (const float*)d_in[2];
  const float* w_kv_a = (const float*)d_in[3];
  const float* ln_w   = (const float*)d_in[4];
  const float* w_kv_b = (const float*)d_in[5];
  const float* w_o    = (const float*)d_in[6];
  float* out = (float*)d_out;

  char* ws = (char*)d_ws;
  size_t off = 0;
  auto alloc = [&](size_t bytes) { void* p = ws + off; off += (bytes + 255) & ~(size_t)255; return p; };
  unsigned short* hs_bf   = (unsigned short*)alloc((size_t)2048 * 2048 * 2);
  unsigned short* wcat_t  = (unsigned short*)alloc((size_t)NPAD1 * 2048 * 2);
  float*          q_lat   = (float*)alloc((size_t)2048 * 640 * 4);   // latent|k_pe|pad f32
  unsigned short* kv_a_bf = (unsigned short*)alloc((size_t)2048 * 512 * 2);
  unsigned short* wkvb_t  = (unsigned short*)alloc((size_t)4096 * 512 * 2);
  unsigned short* kv_b    = (unsigned short*)alloc((size_t)2048 * 4096 * 2);
  unsigned short* q_full  = (unsigned short*)alloc((size_t)NHEAD * 2048 * 192 * 2);
  unsigned short* k_pe    = (unsigned short*)alloc((size_t)2048 * 64 * 2);
  unsigned short* v_t     = (unsigned short*)alloc((size_t)NHEAD * 128 * 2048 * 2);
  unsigned short* attn_o  = (unsigned short*)alloc((size_t)2048 * 2048 * 2);
  unsigned short* wo_t    = (unsigned short*)alloc((size_t)2048 * 2048 * 2);
  float*          rope_tab= (float*)alloc((size_t)2048 * 64 * 4);    // (c,s) interleaved
  float*          part    = (float*)alloc((size_t)512 * PSTRIDE * 4);// flash partials

  prep_kernel<<<17856, 256, 0, stream>>>(hs, w_q, w_kv_a, w_kv_b, w_o, positions,
                                         hs_bf, wcat_t, wkvb_t, wo_t, rope_tab);
  gemm_bt_kernel<128, 2><<<dim3(16, 29), 256, 0, stream>>>(
      hs_bf, wcat_t, q_lat, 2048, NPAD1, 2048, q_full, rope_tab);
  postproc1_kernel<<<2048, 256, 0, stream>>>(q_lat, ln_w, rope_tab, kv_a_bf, k_pe);
  gemm_bt_kernel<128, 1><<<dim3(16, 32), 256, 0, stream>>>(
      kv_a_bf, wkvb_t, kv_b, 2048, 4096, 512, nullptr, nullptr);
  kvpost_kernel<<<4096, 256, 0, stream>>>(kv_b, v_t);
  flash_kernel<<<dim3(16, 48), 256, 0, stream>>>(q_full, kv_b, k_pe, v_t, attn_o, part);
  combine_kernel<<<256, 256, 0, stream>>>(part, attn_o);
  gemm_bt_kernel<64, 0><<<dim3(32, 16), 256, 0, stream>>>(
      attn_o, wo_t, out, 2048, 2048, 2048, nullptr, nullptr);
}

// Round 11
// 251.915 us; speedup vs baseline: 1.0422x; 1.0422x over previous
//
#include <hip/hip_runtime.h>
#include <hip/hip_bf16.h>
#include <stdint.h>

#define T_SEQ   2048
#define NHEAD   16
#define NPAD1   3712   // 3072 (q) + 512 (latent) + 64 (k_pe) + 64 pad -> 29*128

typedef short bf16x8  __attribute__((ext_vector_type(8)));
typedef float f32x4   __attribute__((ext_vector_type(4)));
typedef float f32x16  __attribute__((ext_vector_type(16)));

__device__ __forceinline__ unsigned short f2bf(float f) {
  union { float f; uint32_t u; } v; v.f = f;
  uint32_t u = v.u;
  uint32_t r = u + 0x7FFF + ((u >> 16) & 1);   // RNE
  return (unsigned short)(r >> 16);
}

__device__ __forceinline__ void async16(const void* g, void* l) {
  __builtin_amdgcn_global_load_lds(
      (const __attribute__((address_space(1))) void*)g,
      (__attribute__((address_space(3))) void*)l, 16, 0, 0);
}

// ---------------- fused prep: convert hs + 4 weight transposes + pad + rope table --
__device__ __forceinline__ void tr32(const float* __restrict__ in,
    unsigned short* __restrict__ out, int R, int C, int bx, int by,
    float (*tile)[33], int tid) {
  int r0 = bx * 32, c0 = by * 32;
  int tx = tid & 31, ty = tid >> 5;
  for (int i = 0; i < 4; i++)
    tile[ty + i * 8][tx] = in[(size_t)(r0 + ty + i * 8) * C + c0 + tx];
  __syncthreads();
  for (int i = 0; i < 4; i++) {
    int c = ty + i * 8;
    out[(size_t)(c0 + c) * R + r0 + tx] = f2bf(tile[tx][c]);
  }
}

__global__ __launch_bounds__(256) void prep_kernel(
    const float* __restrict__ hs, const float* __restrict__ w_q,
    const float* __restrict__ w_kv_a, const float* __restrict__ w_kv_b,
    const float* __restrict__ w_o, const int* __restrict__ positions,
    unsigned short* __restrict__ hs_bf, unsigned short* __restrict__ wcat_t,
    unsigned short* __restrict__ wkvb_t, unsigned short* __restrict__ wo_t,
    float* __restrict__ rope_tab) {             // T x 64 f32, interleaved (c,s)
  __shared__ float tile[32][33];
  int bid = blockIdx.x, tid = threadIdx.x;
  if (bid < 4096) {                              // convert hs -> bf16
    int i = (bid * 256 + tid) * 4;
    float4 v = *(const float4*)(hs + i);
    ushort4 o; o.x = f2bf(v.x); o.y = f2bf(v.y); o.z = f2bf(v.z); o.w = f2bf(v.w);
    *(ushort4*)(hs_bf + i) = o;
  } else if (bid < 4096 + 6144) {                // w_q^T (2048x3072)
    int l = bid - 4096;
    tr32(w_q, wcat_t, 2048, 3072, l & 63, l >> 6, tile, tid);
  } else if (bid < 4096 + 6144 + 1152) {         // w_kv_a^T (2048x576)
    int l = bid - (4096 + 6144);
    tr32(w_kv_a, wcat_t + (size_t)3072 * 2048, 2048, 576, l & 63, l >> 6, tile, tid);
  } else if (bid < 4096 + 6144 + 1152 + 2048) {  // w_kv_b^T (512x4096)
    int l = bid - (4096 + 6144 + 1152);
    tr32(w_kv_b, wkvb_t, 512, 4096, l & 15, l >> 4, tile, tid);
  } else if (bid < 4096 + 6144 + 1152 + 2048 + 4096) {  // w_o^T (2048x2048)
    int l = bid - (4096 + 6144 + 1152 + 2048);
    tr32(w_o, wo_t, 2048, 2048, l & 63, l >> 6, tile, tid);
  } else if (bid < 17600) {                      // zero pad rows 3648..3711 of wcat_t
    int l = bid - (4096 + 6144 + 1152 + 2048 + 4096);
    uint4 z = (uint4){0, 0, 0, 0};
    *(uint4*)(wcat_t + (size_t)3648 * 2048 + (size_t)(l * 256 + tid) * 8) = z;
  } else {                                       // rope cos/sin table (trig lives HERE,
    int l = bid - 17600;                         //  never in the GEMM epilogue)
    int t = l * 8 + (tid >> 5), p = tid & 31;
    float pos = (float)positions[t];
    float inv_freq = powf(10000.f, -(float)(2 * p) / 64.f);
    float c, s; sincosf(pos * inv_freq, &s, &c);
    rope_tab[(size_t)t * 64 + 2 * p]     = c;
    rope_tab[(size_t)t * 64 + 2 * p + 1] = s;
  }
}

// ---------------- GEMM: C(MxN) = A(MxK) bf16 @ B^T(NxK) bf16 ----------------
// TM x 128 tile, BK=64, 4 waves of (TM/2)x64. Double-buffered global_load_lds,
// single barrier per K-step (r9 best). Chunk-XOR LDS swizzle both-sides.
// EPI: 0 = f32 C, 2 = fused q-epilogue (gemm1), 3 = fused kv epilogue (gemm2):
//   each 128-col tile is a K-half (cols 256h..+128) or V-half (256h+128..+256),
//   BLOCK-uniform. K-half -> kvk bf16 (T x 2048, K-nope only); V-half ->
//   v_t[(h*128+d)*T + t] transposed via ushort4 (4 consecutive t per thread).
//   kvpost kernel eliminated; kv_b V-write + kvpost read/write traffic gone.
// EPI 2/3 are CALL-FREE and TRIG-FREE (libm in epilogue spills acc: r4/r5).
template<int TM, int EPI>
__global__ __launch_bounds__(256) void gemm_bt_kernel(
    const unsigned short* __restrict__ A, const unsigned short* __restrict__ B,
    void* __restrict__ Cv, int M, int N, int K,
    unsigned short* __restrict__ aux, const float* __restrict__ rope_tab) {
  constexpr int MT = TM / 32;                    // 16-row subtiles per wave
  __shared__ __align__(16) unsigned short Asm[2][TM * 64];
  __shared__ __align__(16) unsigned short Bsm[2][128 * 64];
  int tid = threadIdx.x, wid = tid >> 6, lane = tid & 63;
  int lrow = lane & 15, lquad = lane >> 4;
  int m0 = blockIdx.x * TM, n0 = blockIdx.y * 128;
  int wm = (wid & 1) * (TM / 2), wn = (wid >> 1) * 64;

  int row_s = tid >> 3;                          // 32 rows per 256-thread pass
  int cc_s = (tid & 7) ^ (row_s & 7);            // pre-swizzled source 16B chunk
  const unsigned short* Ag[MT];
  const unsigned short* Bg[4];
  #pragma unroll
  for (int p = 0; p < MT; p++) Ag[p] = A + (size_t)(m0 + row_s + p * 32) * K + cc_s * 8;
  #pragma unroll
  for (int p = 0; p < 4; p++)  Bg[p] = B + (size_t)(n0 + row_s + p * 32) * K + cc_s * 8;

  f32x4 acc[MT][4];
  #pragma unroll
  for (int i = 0; i < MT; i++)
    #pragma unroll
    for (int j = 0; j < 4; j++) acc[i][j] = (f32x4){0.f,0.f,0.f,0.f};

  #pragma unroll
  for (int p = 0; p < MT; p++) async16(Ag[p], &Asm[0][(tid + p * 256) * 8]);
  #pragma unroll
  for (int p = 0; p < 4; p++)  async16(Bg[p], &Bsm[0][(tid + p * 256) * 8]);

  int cur = 0;
  for (int k0 = 0; k0 < K; k0 += 64) {
    __syncthreads();                      // drains DMA for buf[cur]; prev readers done
    if (k0 + 64 < K) {
      int nxt = cur ^ 1, kk = k0 + 64;
      #pragma unroll
      for (int p = 0; p < MT; p++) async16(Ag[p] + kk, &Asm[nxt][(tid + p * 256) * 8]);
      #pragma unroll
      for (int p = 0; p < 4; p++)  async16(Bg[p] + kk, &Bsm[nxt][(tid + p * 256) * 8]);
    }
    const unsigned short* As = Asm[cur];
    const unsigned short* Bs = Bsm[cur];
    int xr = (lrow & 7);
    #pragma unroll
    for (int kk = 0; kk < 2; kk++) {             // two K=32 halves of the 64-step
      int cz = ((kk * 4 + lquad) ^ xr) * 8;      // swizzled chunk (shorts)
      bf16x8 af[MT], bfr[4];
      #pragma unroll
      for (int mt = 0; mt < MT; mt++)
        af[mt] = *(const bf16x8*)(As + (wm + mt * 16 + lrow) * 64 + cz);
      #pragma unroll
      for (int nt = 0; nt < 4; nt++)
        bfr[nt] = *(const bf16x8*)(Bs + (wn + nt * 16 + lrow) * 64 + cz);
      #pragma unroll
      for (int mt = 0; mt < MT; mt++)
        #pragma unroll
        for (int nt = 0; nt < 4; nt++)
          acc[mt][nt] = __builtin_amdgcn_mfma_f32_16x16x32_bf16(af[mt], bfr[nt], acc[mt][nt], 0, 0, 0);
    }
    cur ^= 1;
  }

  if constexpr (EPI == 2) {
    const float scaling = 0.07216878364870323f;  // 192^-0.5
    float* qlat = (float*)Cv;                    // T x 640 (latent 512 | k_pe 64 | pad 64)
    #pragma unroll
    for (int nt = 0; nt < 4; nt++) {
      int colb = n0 + wn + nt * 16;              // wave-uniform, 16-aligned
      if (colb >= 3072) {                        // latent / k_pe / pad -> f32 narrow
        int col = colb - 3072 + lrow;
        #pragma unroll
        for (int mt = 0; mt < MT; mt++) {
          int row = m0 + wm + mt * 16 + lquad * 4;
          #pragma unroll
          for (int r = 0; r < 4; r++)
            qlat[(size_t)(row + r) * 640 + col] = acc[mt][nt][r];
        }
      } else {
        int h = colb / 192;
        int hm = colb - h * 192;                 // uniform; frag never straddles 192 or 128
        unsigned short* qh = aux + (size_t)h * T_SEQ * 192;   // aux = q_full
        if (hm < 128) {                          // q_nope: scale only
          #pragma unroll
          for (int mt = 0; mt < MT; mt++) {
            int row = m0 + wm + mt * 16 + lquad * 4;
            #pragma unroll
            for (int r = 0; r < 4; r++)
              qh[(size_t)(row + r) * 192 + hm + lrow] = f2bf(acc[mt][nt][r] * scaling);
          }
        } else {                                 // q_pe: rope via table (no trig here!)
          int p2 = (hm - 128 + lrow) & ~1;       // 2*p, shared by lane pair
          int odd = lrow & 1;
          #pragma unroll
          for (int mt = 0; mt < MT; mt++) {
            int row = m0 + wm + mt * 16 + lquad * 4;
            #pragma unroll
            for (int r = 0; r < 4; r++) {
              int rg = row + r;
              float c = rope_tab[(size_t)rg * 64 + p2];
              float s = rope_tab[(size_t)rg * 64 + p2 + 1];
              float own = acc[mt][nt][r];
              float oth = __shfl_xor(own, 1, 64);
              float o = odd ? (own * c + oth * s)           // o2 = x2*c + x1*s
                            : (own * c - oth * s);          // o1 = x1*c - x2*s
              qh[(size_t)rg * 192 + hm + lrow] = f2bf(o * scaling);
            }
          }
        }
      }
    }
  } else if constexpr (EPI == 3) {               // gemm2 fused kv epilogue
    int h = n0 >> 8;                             // head (block-uniform)
    if (n0 & 128) {                              // V half -> v_t transposed
      unsigned short* vt = aux;                  // aux = v_t (NH x 128 x T)
      #pragma unroll
      for (int nt = 0; nt < 4; nt++) {
        #pragma unroll
        for (int mt = 0; mt < MT; mt++) {
          int row = m0 + wm + mt * 16 + lquad * 4;
          int dm = wn + nt * 16 + lrow;
          ushort4 o;
          o.x = f2bf(acc[mt][nt][0]); o.y = f2bf(acc[mt][nt][1]);
          o.z = f2bf(acc[mt][nt][2]); o.w = f2bf(acc[mt][nt][3]);
          *(ushort4*)(vt + ((size_t)h * 128 + dm) * T_SEQ + row) = o;
        }
      }
    } else {                                     // K half -> kvk bf16 (T x 2048)
      unsigned short* kvk = (unsigned short*)Cv;
      #pragma unroll
      for (int mt = 0; mt < MT; mt++)
        #pragma unroll
        for (int nt = 0; nt < 4; nt++) {
          int row = m0 + wm + mt * 16 + lquad * 4;
          int col = h * 128 + wn + nt * 16 + lrow;
          #pragma unroll
          for (int r = 0; r < 4; r++)
            kvk[(size_t)(row + r) * 2048 + col] = f2bf(acc[mt][nt][r]);
        }
    }
  } else {
    #pragma unroll
    for (int mt = 0; mt < MT; mt++)
      #pragma unroll
      for (int nt = 0; nt < 4; nt++) {
        int row = m0 + wm + mt * 16 + lquad * 4;
        int col = n0 + wn + nt * 16 + lrow;
        #pragma unroll
        for (int r = 0; r < 4; r++)
          ((float*)Cv)[(size_t)(row + r) * N + col] = acc[mt][nt][r];
      }
  }
}

// ---------------- postproc1: rmsnorm + k_pe rope (table) + kv_a pack ----------------
__global__ __launch_bounds__(256) void postproc1_kernel(
    const float* __restrict__ q_lat,      // T x 640 (latent 512 | k_pe 64 | pad)
    const float* __restrict__ ln_w,       // 512
    const float* __restrict__ rope_tab,   // T x 64 (c,s interleaved)
    unsigned short* __restrict__ kv_a,    // T x 512 bf16
    unsigned short* __restrict__ k_pe)    // T x 64 bf16 (roped)
{
  int t = blockIdx.x, tid = threadIdx.x;
  const float* row = q_lat + (size_t)t * 640;

  float v0 = row[tid], v1 = row[256 + tid];
  float ss = v0 * v0 + v1 * v1;
  for (int m = 1; m < 64; m <<= 1) ss += __shfl_xor(ss, m, 64);
  __shared__ float red[4];
  if ((tid & 63) == 0) red[tid >> 6] = ss;
  __shared__ float kro[64];
  if (tid < 32) {
    float c = rope_tab[(size_t)t * 64 + 2 * tid];
    float s = rope_tab[(size_t)t * 64 + 2 * tid + 1];
    float x1 = row[512 + 2 * tid], x2 = row[512 + 2 * tid + 1];
    kro[2 * tid]     = x1 * c - x2 * s;
    kro[2 * tid + 1] = x2 * c + x1 * s;
  }
  __syncthreads();
  float rstd = rsqrtf((red[0] + red[1] + red[2] + red[3]) * (1.f / 512.f) + 1e-6f);
  kv_a[(size_t)t * 512 + tid]       = f2bf(v0 * rstd * ln_w[tid]);
  kv_a[(size_t)t * 512 + 256 + tid] = f2bf(v1 * rstd * ln_w[256 + tid]);
  if (tid < 64) k_pe[(size_t)t * 64 + tid] = f2bf(kro[tid]);
}

// ---------------- flash attention: BM=64, BN=64, 32x32x16 MFMA (r9 proven) --------
// K staged straight from kvk (nope cols, T x 2048) + k_pe (pe cols); LDS layout
// r4 scheme (row*192, chunk-XOR). Balanced (qb, 31-qb) pairing.
#define PP 76
__global__ __launch_bounds__(256, 2) void flash_kernel(
    const unsigned short* __restrict__ q_full,  // NH x T x 192 (pre-scaled)
    const unsigned short* __restrict__ kvk,     // T x 2048 (K-nope)
    const unsigned short* __restrict__ k_pe,    // T x 64 (roped)
    const unsigned short* __restrict__ v_t,     // NH x 128 x T
    unsigned short* __restrict__ attn_out)      // T x 2048
{
  __shared__ __align__(16) unsigned short Ksm[2][1536 * 8];  // 49152 B
  __shared__ __align__(16) unsigned short Vsm[1024 * 8];     // 16384 B
  __shared__ __align__(16) unsigned short Psm[64 * PP];      //  9728 B
  __shared__ float Lred[2][64];
  int h = blockIdx.x;
  int y = blockIdx.y;
  int qb = (y < 16) ? (31 - y) : (y - 16);     // balanced pairing (sum 31)
  int tid = threadIdx.x, wid = tid >> 6, lane = tid & 63;
  int l31 = lane & 31, l5 = lane >> 5, x7 = l31 & 7;
  int rq = wid & 1, kq = wid >> 1;             // row-half / key-half (dh = kq for PV)

  const unsigned short* vh = v_t + (size_t)h * 128 * T_SEQ;

  // K staging: per-lane source ptr + per-64-row stride (kvk vs k_pe class)
  const unsigned short* pK[6]; int sK[6];
  #pragma unroll
  for (int j = 0; j < 6; j++) {
    int s = tid + j * 256, row = s / 24, cm = s - row * 24;
    int c = cm ^ (row & 7);                    // swizzled 16B chunk of logical row
    if (c < 16) { pK[j] = kvk + (size_t)row * 2048 + h * 128 + c * 8; sK[j] = 64 * 2048; }
    else        { pK[j] = k_pe + (size_t)row * 64 + (c - 16) * 8;     sK[j] = 64 * 64; }
  }
  int gV[4];
  #pragma unroll
  for (int j = 0; j < 4; j++) {
    int s = tid + j * 256, d = s >> 3;
    gV[j] = d * T_SEQ + ((s & 7) ^ (d & 7)) * 8;
  }
  // K frag offsets: key = kq*32+l31, chunk c8 = kc*2+l5 (XOR-unswizzle)
  int kxo[12];
  #pragma unroll
  for (int kc = 0; kc < 12; kc++)
    kxo[kc] = (kq * 32 + l31) * 192 + ((kc * 2 + l5) ^ x7) * 8;
  // V frag bases: d = kq*64 + ntv*32 + l31
  int vxb[2];
  #pragma unroll
  for (int ntv = 0; ntv < 2; ntv++) vxb[ntv] = (kq * 64 + ntv * 32 + l31) * 64;

  bf16x8 qf[12];
  {
    const unsigned short* qrow =
        q_full + ((size_t)h * T_SEQ + qb * 64 + rq * 32 + l31) * 192 + l5 * 8;
    #pragma unroll
    for (int kc = 0; kc < 12; kc++) qf[kc] = *(const bf16x8*)(qrow + kc * 16);
  }
  f32x16 oacc[2];
  for (int i = 0; i < 2; i++) oacc[i] = (f32x16)(0.f);
  float lsum[16];
  #pragma unroll
  for (int r = 0; r < 16; r++) lsum[r] = 0.f;
  int rl[16];                                   // C/D reg -> local row (32x32 layout)
  #pragma unroll
  for (int r = 0; r < 16; r++) rl[r] = (r & 3) + 8 * (r >> 2) + 4 * l5;

  // prologue: stage K(0) into buf 0
  #pragma unroll
  for (int j = 0; j < 6; j++) async16(pK[j], &Ksm[0][(tid + j * 256) * 8]);

  int cur = 0;
  for (int kb = 0; kb <= qb; kb++) {
    __syncthreads();                            // K[cur] ready; prev PV readers done
    {                                           // stage V(kb); drains at sync2
      const unsigned short* vb = vh + kb * 64;
      #pragma unroll
      for (int j = 0; j < 4; j++) async16(vb + gV[j], &Vsm[(tid + j * 256) * 8]);
    }
    const unsigned short* Ks = Ksm[cur];
    f32x16 sacc = (f32x16)(0.f);
    #pragma unroll
    for (int kc = 0; kc < 12; kc++) {
      bf16x8 kf = *(const bf16x8*)(Ks + kxo[kc]);
      sacc = __builtin_amdgcn_mfma_f32_32x32x16_bf16(qf[kc], kf, sacc, 0, 0, 0);
    }
    if (kb == qb) {                             // mask diagonal tile
      int col_g = kb * 64 + kq * 32 + l31;
      int row_b = qb * 64 + rq * 32;
      #pragma unroll
      for (int r = 0; r < 16; r++)
        if (col_g > row_b + rl[r]) sacc[r] = -1e30f;
    }
    #pragma unroll
    for (int r = 0; r < 16; r++) {
      float p = __expf(sacc[r]);
      sacc[r] = p;
      lsum[r] += p;
    }
    #pragma unroll
    for (int r = 0; r < 16; r++)                // P C-layout -> Psm
      Psm[(rq * 32 + rl[r]) * PP + kq * 32 + l31] = f2bf(sacc[r]);
    __syncthreads();                            // V ready, P visible, K[cur] reads done
    if (kb < qb) {                              // stage K(kb+1); drains at next sync1
      #pragma unroll
      for (int j = 0; j < 6; j++)
        async16(pK[j] + (size_t)(kb + 1) * sK[j], &Ksm[cur ^ 1][(tid + j * 256) * 8]);
    }
    #pragma unroll
    for (int kc = 0; kc < 4; kc++) {            // O += P V
      bf16x8 pf = *(const bf16x8*)(Psm + (rq * 32 + l31) * PP + kc * 16 + l5 * 8);
      #pragma unroll
      for (int ntv = 0; ntv < 2; ntv++) {
        bf16x8 vf = *(const bf16x8*)(Vsm + vxb[ntv] + ((kc * 2 + l5) ^ x7) * 8);
        oacc[ntv] = __builtin_amdgcn_mfma_f32_32x32x16_bf16(pf, vf, oacc[ntv], 0, 0, 0);
      }
    }
    cur ^= 1;
  }

  // denominator: reduce over 32 key-lanes, then combine key-halves via LDS
  #pragma unroll
  for (int r = 0; r < 16; r++) {
    float s = lsum[r];
    s += __shfl_xor(s, 1, 64);
    s += __shfl_xor(s, 2, 64);
    s += __shfl_xor(s, 4, 64);
    s += __shfl_xor(s, 8, 64);
    s += __shfl_xor(s, 16, 64);
    lsum[r] = s;
  }
  if (l31 == 0)
    #pragma unroll
    for (int r = 0; r < 16; r++) Lred[kq][rq * 32 + rl[r]] = lsum[r];
  __syncthreads();
  #pragma unroll
  for (int r = 0; r < 16; r++) {
    int row_l = rq * 32 + rl[r];
    float inv = 1.f / (Lred[0][row_l] + Lred[1][row_l]);
    int row_g = qb * 64 + row_l;
    #pragma unroll
    for (int ntv = 0; ntv < 2; ntv++)
      attn_out[(size_t)row_g * 2048 + h * 128 + kq * 64 + ntv * 32 + l31] =
          f2bf(oacc[ntv][r] * inv);
  }
}

// ---------------- launch ----------------
extern "C" void kernel_launch(void* const* d_in, const int* in_sizes, int n_in,
                              void* d_out, int out_size, void* d_ws, size_t ws_size,
                              hipStream_t stream) {
  const int*   positions = (const int*)d_in[0];
  const float* hs     = (const float*)d_in[1];
  const float* w_q    = (const float*)d_in[2];
  const float* w_kv_a = (const float*)d_in[3];
  const float* ln_w   = (const float*)d_in[4];
  const float* w_kv_b = (const float*)d_in[5];
  const float* w_o    = (const float*)d_in[6];
  float* out = (float*)d_out;

  char* ws = (char*)d_ws;
  size_t off = 0;
  auto alloc = [&](size_t bytes) { void* p = ws + off; off += (bytes + 255) & ~(size_t)255; return p; };
  unsigned short* hs_bf   = (unsigned short*)alloc((size_t)2048 * 2048 * 2);
  unsigned short* wcat_t  = (unsigned short*)alloc((size_t)NPAD1 * 2048 * 2);
  float*          q_lat   = (float*)alloc((size_t)2048 * 640 * 4);   // latent|k_pe|pad f32
  unsigned short* kv_a_bf = (unsigned short*)alloc((size_t)2048 * 512 * 2);
  unsigned short* wkvb_t  = (unsigned short*)alloc((size_t)4096 * 512 * 2);
  unsigned short* kvk     = (unsigned short*)alloc((size_t)2048 * 2048 * 2);  // K-nope only
  unsigned short* q_full  = (unsigned short*)alloc((size_t)NHEAD * 2048 * 192 * 2);
  unsigned short* k_pe    = (unsigned short*)alloc((size_t)2048 * 64 * 2);
  unsigned short* v_t     = (unsigned short*)alloc((size_t)NHEAD * 128 * 2048 * 2);
  unsigned short* attn_o  = (unsigned short*)alloc((size_t)2048 * 2048 * 2);
  unsigned short* wo_t    = (unsigned short*)alloc((size_t)2048 * 2048 * 2);
  float*          rope_tab= (float*)alloc((size_t)2048 * 64 * 4);    // (c,s) interleaved

  prep_kernel<<<17856, 256, 0, stream>>>(hs, w_q, w_kv_a, w_kv_b, w_o, positions,
                                         hs_bf, wcat_t, wkvb_t, wo_t, rope_tab);
  gemm_bt_kernel<128, 2><<<dim3(16, 29), 256, 0, stream>>>(
      hs_bf, wcat_t, q_lat, 2048, NPAD1, 2048, q_full, rope_tab);
  postproc1_kernel<<<2048, 256, 0, stream>>>(q_lat, ln_w, rope_tab, kv_a_bf, k_pe);
  gemm_bt_kernel<128, 3><<<dim3(16, 32), 256, 0, stream>>>(
      kv_a_bf, wkvb_t, kvk, 2048, 4096, 512, v_t, nullptr);
  flash_kernel<<<dim3(16, 32), 256, 0, stream>>>(q_full, kvk, k_pe, v_t, attn_o);
  gemm_bt_kernel<64, 0><<<dim3(32, 16), 256, 0, stream>>>(
      attn_o, wo_t, out, 2048, 2048, 2048, nullptr, nullptr);
}